// Round 2
// baseline (233.412 us; speedup 1.0000x reference)
//
#include <hip/hip_runtime.h>
#include <hip/hip_bf16.h>

typedef __bf16 bf16;
typedef __bf16 bf16x8 __attribute__((ext_vector_type(8)));
typedef __bf16 bf16x4 __attribute__((ext_vector_type(4)));
typedef float  f32x4  __attribute__((ext_vector_type(4)));

#define MFMA16(a,b,c) __builtin_amdgcn_mfma_f32_16x16x32_bf16((a),(b),(c),0,0,0)

__device__ __forceinline__ void gload_lds16(const void* g, void* l) {
    __builtin_amdgcn_global_load_lds(
        (const __attribute__((address_space(1))) void*)g,
        (__attribute__((address_space(3))) void*)l, 16, 0, 0);
}

// Problem sizes: B=512, T=256, C=512, H=64
// ws layout (bytes):
//   WT  [3][64][512] bf16  @ 0          (196,608)
//   Qw  [B*T][64]    bf16  @ 196608
//   Kw  [B*T][64]    bf16  @ 16973824
//   VTw [B][64][256] bf16  @ 33751040

// ---------------- kernel 0: W [512][64] f32 -> WT [64][512] bf16 (x3) -------
__global__ void __launch_bounds__(256) wt_transpose_kernel(
        const float* __restrict__ Wq, const float* __restrict__ Wk,
        const float* __restrict__ Wv, bf16* __restrict__ WT) {
    int tid = blockIdx.x * 256 + threadIdx.x;        // 3*64*512 = 98304
    int wi = tid >> 15;
    int n  = (tid >> 9) & 63;
    int k  = tid & 511;
    const float* W = (wi == 0) ? Wq : ((wi == 1) ? Wk : Wv);
    WT[tid] = (bf16)W[k * 64 + n];
}

// ---------------- kernel 1: projections (async LDS-staged streaming GEMM) ---
// grid 2048, block 256 (4 waves). Block: 64 rows x 192 cols, K-chunks of 64.
// x-tile [64][64] f32 staged via global_load_lds (linear dest, XOR-swizzled
// source at 16B-unit granularity: uP = uL ^ (row&7)); double-buffered (32 KB).
// Wave w owns rows w*16..+16. B-frags read directly from L1/L2-resident WT.
__global__ void __launch_bounds__(256, 4) proj_kernel(
        const float* __restrict__ x, const bf16* __restrict__ WT,
        bf16* __restrict__ Qw, bf16* __restrict__ Kw, bf16* __restrict__ VTw) {
    __shared__ float xtile[2][64 * 64];   // 2 x 16 KB

    const int tid = threadIdx.x;
    const int l   = tid & 63;
    const int w   = tid >> 6;
    const int lo  = l & 15;
    const int hi  = l >> 4;
    const int row0 = blockIdx.x * 64;
    const char* xb = (const char*)x;

    f32x4 acc[12];
    #pragma unroll
    for (int nf = 0; nf < 12; ++nf) acc[nf] = (f32x4){0.f, 0.f, 0.f, 0.f};

    // ---- staging: 1024 units of 16B; wave w, inst j covers units w*256+j*64+lane
    auto stage = [&](int buf, int kc) {
        #pragma unroll
        for (int j = 0; j < 4; ++j) {
            const int s   = w * 256 + j * 64 + l;
            const int row = s >> 4;
            const int uP  = s & 15;
            const int uL  = uP ^ (row & 7);
            const char* src = xb + (size_t)(row0 + row) * 2048 + kc * 256 + uL * 16;
            char* dst = (char*)(&xtile[buf][0]) + s * 16;
            gload_lds16(src, dst);
        }
    };

    stage(0, 0);

    #pragma unroll 1
    for (int kc = 0; kc < 8; ++kc) {
        const int cur = kc & 1;
        __syncthreads();                  // vmcnt(0) drain => buf[cur] ready
        if (kc < 7) stage(cur ^ 1, kc + 1);

        // A-frags from swizzled LDS: row w*16+lo, logical units ks*8+hi*2, +1
        const int rowl = w * 16 + lo;
        bf16x8 a[2];
        #pragma unroll
        for (int ks = 0; ks < 2; ++ks) {
            const int uL0 = ks * 8 + hi * 2;
            const int uP0 = uL0 ^ (lo & 7);
            const int uP1 = (uL0 + 1) ^ (lo & 7);
            f32x4 u0 = *(const f32x4*)&xtile[cur][rowl * 64 + uP0 * 4];
            f32x4 u1 = *(const f32x4*)&xtile[cur][rowl * 64 + uP1 * 4];
            bf16x8 t;
            t[0] = (bf16)u0[0]; t[1] = (bf16)u0[1]; t[2] = (bf16)u0[2]; t[3] = (bf16)u0[3];
            t[4] = (bf16)u1[0]; t[5] = (bf16)u1[1]; t[6] = (bf16)u1[2]; t[7] = (bf16)u1[3];
            a[ks] = t;
        }

        // B-frags direct from WT (L1/L2-resident), interleaved with MFMA
        const bf16* wp = WT + kc * 64 + hi * 8;
        #pragma unroll
        for (int nf = 0; nf < 12; ++nf) {
            const bf16* rp = wp + (nf * 16 + lo) * 512;
            bf16x8 b0 = *(const bf16x8*)(rp);
            bf16x8 b1 = *(const bf16x8*)(rp + 32);
            acc[nf] = MFMA16(a[0], b0, acc[nf]);
            acc[nf] = MFMA16(a[1], b1, acc[nf]);
        }
    }

    // Epilogue. D-frag: n = lo (+nf*16), m = hi*4 + i.
    const int m0   = row0 + w * 16;
    const int bidx = m0 >> 8;
    const int t0b  = m0 & 255;
    #pragma unroll
    for (int nf = 0; nf < 12; ++nf) {
        const int nn   = nf * 16 + lo;
        const int mrow = m0 + hi * 4;
        if (nf < 4) {
            #pragma unroll
            for (int i = 0; i < 4; ++i)
                Qw[(mrow + i) * 64 + nn] = (bf16)acc[nf][i];
        } else if (nf < 8) {
            #pragma unroll
            for (int i = 0; i < 4; ++i)
                Kw[(mrow + i) * 64 + (nn - 64)] = (bf16)acc[nf][i];
        } else {
            bf16x4 pk;
            pk[0] = (bf16)acc[nf][0]; pk[1] = (bf16)acc[nf][1];
            pk[2] = (bf16)acc[nf][2]; pk[3] = (bf16)acc[nf][3];
            *(bf16x4*)(VTw + ((bidx * 64 + (nn - 128)) * 256 + t0b + hi * 4)) = pk;
        }
    }
}

// ---------------- kernel 2: causal flash attention --------------------------
// grid 512 (one block per batch), block 256 (4 waves).
// Wave w owns q-rows {qf*64 + w*16 + lo} (interleaved -> balanced causal work).
// S^T = mfma(A=K, B=Q^T); O^T = mfma(A=V^T, B=P^T) via per-wave LDS P buffer.
__global__ void __launch_bounds__(256, 2) attn_kernel(
        const bf16* __restrict__ Qw, const bf16* __restrict__ Kw,
        const bf16* __restrict__ VTw, float* __restrict__ out) {
    __shared__ bf16 Klds[256][72];      // padded: row stride 144B
    __shared__ bf16 Plds[4][16][72];    // per-wave P buffer [q(16)][key(64)+pad]

    const int tid = threadIdx.x;
    const int l   = tid & 63;
    const int w   = tid >> 6;
    const int lo  = l & 15;
    const int hi  = l >> 4;
    const int b   = blockIdx.x;

    // Stage K [256][64] -> LDS (coalesced: 8 lanes per row)
    {
        const bf16* src = Kw + b * (256 * 64);
        const int r0 = tid >> 3;
        const int cc = (tid & 7) * 8;
        #pragma unroll
        for (int p = 0; p < 8; ++p) {
            const int row = p * 32 + r0;
            *(bf16x8*)&Klds[row][cc] = *(const bf16x8*)(src + row * 64 + cc);
        }
    }
    __syncthreads();

    bf16x8 qfr[4][2];
    #pragma unroll
    for (int qf = 0; qf < 4; ++qf)
        #pragma unroll
        for (int ks = 0; ks < 2; ++ks)
            qfr[qf][ks] = *(const bf16x8*)(Qw + b * 16384 +
                              (qf * 64 + w * 16 + lo) * 64 + ks * 32 + hi * 8);

    f32x4 o[4][4];
    #pragma unroll
    for (int qf = 0; qf < 4; ++qf)
        #pragma unroll
        for (int mf = 0; mf < 4; ++mf)
            o[qf][mf] = (f32x4){0.f, 0.f, 0.f, 0.f};
    float m2[4]   = {-INFINITY, -INFINITY, -INFINITY, -INFINITY};
    float lsum[4] = {0.f, 0.f, 0.f, 0.f};

    const float SC = 0.125f * 1.44269504088896340736f;  // scale * log2(e)

    #pragma unroll
    for (int kc = 0; kc < 4; ++kc) {
        bf16x8 vf[4][2];
        #pragma unroll
        for (int mf = 0; mf < 4; ++mf)
            #pragma unroll
            for (int ks = 0; ks < 2; ++ks)
                vf[mf][ks] = *(const bf16x8*)(VTw + (b * 64 + mf * 16 + lo) * 256 +
                                              kc * 64 + ks * 32 + hi * 8);

        #pragma unroll
        for (int qf = kc; qf < 4; ++qf) {
            f32x4 s[4];
            #pragma unroll
            for (int kf = 0; kf < 4; ++kf) {
                bf16x8 k0 = *(const bf16x8*)&Klds[kc * 64 + kf * 16 + lo][hi * 8];
                bf16x8 k1 = *(const bf16x8*)&Klds[kc * 64 + kf * 16 + lo][32 + hi * 8];
                f32x4 t = (f32x4){0.f, 0.f, 0.f, 0.f};
                t = MFMA16(k0, qfr[qf][0], t);
                t = MFMA16(k1, qfr[qf][1], t);
                s[kf] = t;
            }
            float mx = -INFINITY;
            #pragma unroll
            for (int kf = 0; kf < 4; ++kf)
                #pragma unroll
                for (int i = 0; i < 4; ++i) {
                    float v = s[kf][i] * SC;
                    if (kc == qf && (kf * 16 + hi * 4 + i) > (w * 16 + lo)) v = -INFINITY;
                    s[kf][i] = v;
                    mx = fmaxf(mx, v);
                }
            mx = fmaxf(mx, __shfl_xor(mx, 16));
            mx = fmaxf(mx, __shfl_xor(mx, 32));
            const float mnew = fmaxf(m2[qf], mx);
            const float rsc  = exp2f(m2[qf] - mnew);
            m2[qf] = mnew;

            float cs = 0.f;
            bf16x4 pk[4];
            #pragma unroll
            for (int kf = 0; kf < 4; ++kf)
                #pragma unroll
                for (int i = 0; i < 4; ++i) {
                    float p = exp2f(s[kf][i] - mnew);
                    cs += p;
                    pk[kf][i] = (bf16)p;
                }
            cs += __shfl_xor(cs, 16);
            cs += __shfl_xor(cs, 32);
            lsum[qf] = lsum[qf] * rsc + cs;

            #pragma unroll
            for (int kf = 0; kf < 4; ++kf)
                *(bf16x4*)&Plds[w][lo][kf * 16 + hi * 4] = pk[kf];

            #pragma unroll
            for (int mf = 0; mf < 4; ++mf) {
                o[qf][mf][0] *= rsc; o[qf][mf][1] *= rsc;
                o[qf][mf][2] *= rsc; o[qf][mf][3] *= rsc;
            }
            #pragma unroll
            for (int ks = 0; ks < 2; ++ks) {
                bf16x8 pf = *(const bf16x8*)&Plds[w][lo][ks * 32 + hi * 8];
                #pragma unroll
                for (int mf = 0; mf < 4; ++mf)
                    o[qf][mf] = MFMA16(vf[mf][ks], pf, o[qf][mf]);
            }
        }
    }

    #pragma unroll
    for (int qf = 0; qf < 4; ++qf) {
        const float inv = 1.0f / lsum[qf];
        const int q = qf * 64 + w * 16 + lo;
        #pragma unroll
        for (int mf = 0; mf < 4; ++mf) {
            f32x4 r4;
            r4[0] = o[qf][mf][0] * inv; r4[1] = o[qf][mf][1] * inv;
            r4[2] = o[qf][mf][2] * inv; r4[3] = o[qf][mf][3] * inv;
            *(f32x4*)(out + (b * 256 + q) * 64 + mf * 16 + hi * 4) = r4;
        }
    }
}

// ---------------- launcher --------------------------------------------------
extern "C" void kernel_launch(void* const* d_in, const int* in_sizes, int n_in,
                              void* d_out, int out_size, void* d_ws, size_t ws_size,
                              hipStream_t stream) {
    const float* x  = (const float*)d_in[0];
    const float* Wq = (const float*)d_in[1];
    const float* Wk = (const float*)d_in[2];
    const float* Wv = (const float*)d_in[3];
    float* out = (float*)d_out;

    char* ws = (char*)d_ws;
    bf16* WT  = (bf16*)(ws);
    bf16* Qw  = (bf16*)(ws + 196608);
    bf16* Kw  = (bf16*)(ws + 16973824);
    bf16* VTw = (bf16*)(ws + 33751040);

    wt_transpose_kernel<<<dim3(384), dim3(256), 0, stream>>>(Wq, Wk, Wv, WT);
    proj_kernel<<<dim3(2048), dim3(256), 0, stream>>>(x, WT, Qw, Kw, VTw);
    attn_kernel<<<dim3(512), dim3(256), 0, stream>>>(Qw, Kw, VTw, out);
}

// Round 3
// 156.302 us; speedup vs baseline: 1.4933x; 1.4933x over previous
//
#include <hip/hip_runtime.h>
#include <hip/hip_bf16.h>

typedef __bf16 bf16;
typedef __bf16 bf16x8 __attribute__((ext_vector_type(8)));
typedef __bf16 bf16x4 __attribute__((ext_vector_type(4)));
typedef float  f32x4  __attribute__((ext_vector_type(4)));

#define MFMA16(a,b,c) __builtin_amdgcn_mfma_f32_16x16x32_bf16((a),(b),(c),0,0,0)

// Problem sizes: B=512, T=256, C=512, H=64
// ws layout (bytes):
//   WT  [3][64][512] bf16  @ 0          (196,608)
//   Qw  [B*T][64]    bf16  @ 196608
//   Kw  [B*T][64]    bf16  @ 16973824
//   VTw [B][64][256] bf16  @ 33751040

// ---------------- kernel 0: W [512][64] f32 -> WT [64][512] bf16 (x3) -------
__global__ void __launch_bounds__(256) wt_transpose_kernel(
        const float* __restrict__ Wq, const float* __restrict__ Wk,
        const float* __restrict__ Wv, bf16* __restrict__ WT) {
    int tid = blockIdx.x * 256 + threadIdx.x;        // 3*64*512 = 98304
    int wi = tid >> 15;
    int n  = (tid >> 9) & 63;
    int k  = tid & 511;
    const float* W = (wi == 0) ? Wq : ((wi == 1) ? Wk : Wv);
    WT[tid] = (bf16)W[k * 64 + n];
}

// ---------------- kernel 1: projections (no LDS, batched-load streaming) ----
// grid 1024, block 256 (4 waves). Wave w: 32 rows (mf=2) x 192 cols.
// K-chunks of 32. Per chunk: 12 B-frags loaded BATCHED into regs (one vmcnt
// wait, not a serial chain), x loaded with 1-deep prefetch. No barriers.
__global__ void __launch_bounds__(256, 2) proj_kernel(
        const float* __restrict__ x, const bf16* __restrict__ WT,
        bf16* __restrict__ Qw, bf16* __restrict__ Kw, bf16* __restrict__ VTw) {
    const int l  = threadIdx.x & 63;
    const int w  = threadIdx.x >> 6;
    const int lo = l & 15;
    const int hi = l >> 4;
    const int m0 = blockIdx.x * 128 + w * 32;

    const float* xr0 = x + (size_t)(m0 + lo) * 512 + hi * 8;        // mf=0 row
    const float* xr1 = xr0 + 16 * 512;                              // mf=1 row
    const bf16*  wb  = WT + lo * 512 + hi * 8;

    f32x4 acc[2][12];
    #pragma unroll
    for (int mf = 0; mf < 2; ++mf)
        #pragma unroll
        for (int nf = 0; nf < 12; ++nf)
            acc[mf][nf] = (f32x4){0.f, 0.f, 0.f, 0.f};

    // preload chunk 0 x
    f32x4 xc[2][2];
    xc[0][0] = *(const f32x4*)(xr0);
    xc[0][1] = *(const f32x4*)(xr0 + 4);
    xc[1][0] = *(const f32x4*)(xr1);
    xc[1][1] = *(const f32x4*)(xr1 + 4);

    #pragma unroll 1
    for (int kc = 0; kc < 16; ++kc) {
        // convert current x -> A frags (consumes xc)
        bf16x8 a[2];
        #pragma unroll
        for (int mf = 0; mf < 2; ++mf) {
            bf16x8 t;
            t[0] = (bf16)xc[mf][0][0]; t[1] = (bf16)xc[mf][0][1];
            t[2] = (bf16)xc[mf][0][2]; t[3] = (bf16)xc[mf][0][3];
            t[4] = (bf16)xc[mf][1][0]; t[5] = (bf16)xc[mf][1][1];
            t[6] = (bf16)xc[mf][1][2]; t[7] = (bf16)xc[mf][1][3];
            a[mf] = t;
        }
        // issue next chunk's x loads immediately (1-deep prefetch;
        // consumed at next iteration's cvt, ~300+ cyc later)
        {
            const int kn = (kc + 1) & 15;
            xc[0][0] = *(const f32x4*)(xr0 + kn * 32);
            xc[0][1] = *(const f32x4*)(xr0 + kn * 32 + 4);
            xc[1][0] = *(const f32x4*)(xr1 + kn * 32);
            xc[1][1] = *(const f32x4*)(xr1 + kn * 32 + 4);
        }
        // batched B-frag loads: 12 independent 16B loads, issued back-to-back
        bf16x8 barr[12];
        #pragma unroll
        for (int nf = 0; nf < 12; ++nf)
            barr[nf] = *(const bf16x8*)(wb + nf * 8192 + kc * 32);
        // MFMAs (each B reused for 2 row-frags)
        #pragma unroll
        for (int nf = 0; nf < 12; ++nf) {
            acc[0][nf] = MFMA16(a[0], barr[nf], acc[0][nf]);
            acc[1][nf] = MFMA16(a[1], barr[nf], acc[1][nf]);
        }
    }

    // Epilogue. D-frag: n = lo (+nf*16), m = hi*4 + i (+mf*16).
    const int bidx = m0 >> 8;        // batch
    const int t0b  = m0 & 255;       // t base within batch
    #pragma unroll
    for (int nf = 0; nf < 12; ++nf) {
        const int nn = nf * 16 + lo;
        #pragma unroll
        for (int mf = 0; mf < 2; ++mf) {
            const int mrow = m0 + mf * 16 + hi * 4;
            if (nf < 4) {
                #pragma unroll
                for (int i = 0; i < 4; ++i)
                    Qw[(mrow + i) * 64 + nn] = (bf16)acc[mf][nf][i];
            } else if (nf < 8) {
                #pragma unroll
                for (int i = 0; i < 4; ++i)
                    Kw[(mrow + i) * 64 + (nn - 64)] = (bf16)acc[mf][nf][i];
            } else {
                // V stored transposed: VT[b][h][t]; lane's 4 values are consecutive t
                bf16x4 pk;
                pk[0] = (bf16)acc[mf][nf][0]; pk[1] = (bf16)acc[mf][nf][1];
                pk[2] = (bf16)acc[mf][nf][2]; pk[3] = (bf16)acc[mf][nf][3];
                const int t0 = t0b + mf * 16 + hi * 4;
                *(bf16x4*)(VTw + ((bidx * 64 + (nn - 128)) * 256 + t0)) = pk;
            }
        }
    }
}

// ---------------- kernel 2: causal flash attention --------------------------
// grid 512 (one block per batch), block 256 (4 waves).
// Wave w owns q-rows {qf*64 + w*16 + lo} (interleaved -> balanced causal work).
// S^T = mfma(A=K, B=Q^T); O^T = mfma(A=V^T, B=P^T) via per-wave LDS P buffer.
__global__ void __launch_bounds__(256, 2) attn_kernel(
        const bf16* __restrict__ Qw, const bf16* __restrict__ Kw,
        const bf16* __restrict__ VTw, float* __restrict__ out) {
    __shared__ bf16 Klds[256][72];      // padded: row stride 144B
    __shared__ bf16 Plds[4][16][72];    // per-wave P buffer [q(16)][key(64)+pad]

    const int tid = threadIdx.x;
    const int l   = tid & 63;
    const int w   = tid >> 6;
    const int lo  = l & 15;
    const int hi  = l >> 4;
    const int b   = blockIdx.x;

    // Stage K [256][64] -> LDS (coalesced: 8 lanes per row)
    {
        const bf16* src = Kw + b * (256 * 64);
        const int r0 = tid >> 3;
        const int cc = (tid & 7) * 8;
        #pragma unroll
        for (int p = 0; p < 8; ++p) {
            const int row = p * 32 + r0;
            *(bf16x8*)&Klds[row][cc] = *(const bf16x8*)(src + row * 64 + cc);
        }
    }
    __syncthreads();

    bf16x8 qfr[4][2];
    #pragma unroll
    for (int qf = 0; qf < 4; ++qf)
        #pragma unroll
        for (int ks = 0; ks < 2; ++ks)
            qfr[qf][ks] = *(const bf16x8*)(Qw + b * 16384 +
                              (qf * 64 + w * 16 + lo) * 64 + ks * 32 + hi * 8);

    f32x4 o[4][4];
    #pragma unroll
    for (int qf = 0; qf < 4; ++qf)
        #pragma unroll
        for (int mf = 0; mf < 4; ++mf)
            o[qf][mf] = (f32x4){0.f, 0.f, 0.f, 0.f};
    float m2[4]   = {-INFINITY, -INFINITY, -INFINITY, -INFINITY};
    float lsum[4] = {0.f, 0.f, 0.f, 0.f};

    const float SC = 0.125f * 1.44269504088896340736f;  // scale * log2(e)

    #pragma unroll
    for (int kc = 0; kc < 4; ++kc) {
        bf16x8 vf[4][2];
        #pragma unroll
        for (int mf = 0; mf < 4; ++mf)
            #pragma unroll
            for (int ks = 0; ks < 2; ++ks)
                vf[mf][ks] = *(const bf16x8*)(VTw + (b * 64 + mf * 16 + lo) * 256 +
                                              kc * 64 + ks * 32 + hi * 8);

        #pragma unroll
        for (int qf = kc; qf < 4; ++qf) {
            f32x4 s[4];
            #pragma unroll
            for (int kf = 0; kf < 4; ++kf) {
                bf16x8 k0 = *(const bf16x8*)&Klds[kc * 64 + kf * 16 + lo][hi * 8];
                bf16x8 k1 = *(const bf16x8*)&Klds[kc * 64 + kf * 16 + lo][32 + hi * 8];
                f32x4 t = (f32x4){0.f, 0.f, 0.f, 0.f};
                t = MFMA16(k0, qfr[qf][0], t);
                t = MFMA16(k1, qfr[qf][1], t);
                s[kf] = t;
            }
            float mx = -INFINITY;
            #pragma unroll
            for (int kf = 0; kf < 4; ++kf)
                #pragma unroll
                for (int i = 0; i < 4; ++i) {
                    float v = s[kf][i] * SC;
                    if (kc == qf && (kf * 16 + hi * 4 + i) > (w * 16 + lo)) v = -INFINITY;
                    s[kf][i] = v;
                    mx = fmaxf(mx, v);
                }
            mx = fmaxf(mx, __shfl_xor(mx, 16));
            mx = fmaxf(mx, __shfl_xor(mx, 32));
            const float mnew = fmaxf(m2[qf], mx);
            const float rsc  = exp2f(m2[qf] - mnew);
            m2[qf] = mnew;

            float cs = 0.f;
            bf16x4 pk[4];
            #pragma unroll
            for (int kf = 0; kf < 4; ++kf)
                #pragma unroll
                for (int i = 0; i < 4; ++i) {
                    float p = exp2f(s[kf][i] - mnew);
                    cs += p;
                    pk[kf][i] = (bf16)p;
                }
            cs += __shfl_xor(cs, 16);
            cs += __shfl_xor(cs, 32);
            lsum[qf] = lsum[qf] * rsc + cs;

            #pragma unroll
            for (int kf = 0; kf < 4; ++kf)
                *(bf16x4*)&Plds[w][lo][kf * 16 + hi * 4] = pk[kf];

            #pragma unroll
            for (int mf = 0; mf < 4; ++mf) {
                o[qf][mf][0] *= rsc; o[qf][mf][1] *= rsc;
                o[qf][mf][2] *= rsc; o[qf][mf][3] *= rsc;
            }
            #pragma unroll
            for (int ks = 0; ks < 2; ++ks) {
                bf16x8 pf = *(const bf16x8*)&Plds[w][lo][ks * 32 + hi * 8];
                #pragma unroll
                for (int mf = 0; mf < 4; ++mf)
                    o[qf][mf] = MFMA16(vf[mf][ks], pf, o[qf][mf]);
            }
        }
    }

    #pragma unroll
    for (int qf = 0; qf < 4; ++qf) {
        const float inv = 1.0f / lsum[qf];
        const int q = qf * 64 + w * 16 + lo;
        #pragma unroll
        for (int mf = 0; mf < 4; ++mf) {
            f32x4 r4;
            r4[0] = o[qf][mf][0] * inv; r4[1] = o[qf][mf][1] * inv;
            r4[2] = o[qf][mf][2] * inv; r4[3] = o[qf][mf][3] * inv;
            *(f32x4*)(out + (b * 256 + q) * 64 + mf * 16 + hi * 4) = r4;
        }
    }
}

// ---------------- launcher --------------------------------------------------
extern "C" void kernel_launch(void* const* d_in, const int* in_sizes, int n_in,
                              void* d_out, int out_size, void* d_ws, size_t ws_size,
                              hipStream_t stream) {
    const float* x  = (const float*)d_in[0];
    const float* Wq = (const float*)d_in[1];
    const float* Wk = (const float*)d_in[2];
    const float* Wv = (const float*)d_in[3];
    float* out = (float*)d_out;

    char* ws = (char*)d_ws;
    bf16* WT  = (bf16*)(ws);
    bf16* Qw  = (bf16*)(ws + 196608);
    bf16* Kw  = (bf16*)(ws + 16973824);
    bf16* VTw = (bf16*)(ws + 33751040);

    wt_transpose_kernel<<<dim3(384), dim3(256), 0, stream>>>(Wq, Wk, Wv, WT);
    proj_kernel<<<dim3(1024), dim3(256), 0, stream>>>(x, WT, Qw, Kw, VTw);
    attn_kernel<<<dim3(512), dim3(256), 0, stream>>>(Qw, Kw, VTw, out);
}

// Round 4
// 117.932 us; speedup vs baseline: 1.9792x; 1.3254x over previous
//
#include <hip/hip_runtime.h>
#include <hip/hip_bf16.h>

typedef __bf16 bf16;
typedef __bf16 bf16x8 __attribute__((ext_vector_type(8)));
typedef __bf16 bf16x4 __attribute__((ext_vector_type(4)));
typedef float  f32x4  __attribute__((ext_vector_type(4)));

#define MFMA16(a,b,c) __builtin_amdgcn_mfma_f32_16x16x32_bf16((a),(b),(c),0,0,0)

__device__ __forceinline__ void gload_lds16(const void* g, void* l) {
    __builtin_amdgcn_global_load_lds(
        (const __attribute__((address_space(1))) void*)g,
        (__attribute__((address_space(3))) void*)l, 16, 0, 0);
}

// Problem sizes: B=512, T=256, C=512, H=64
// ws layout (bytes):
//   WTfrag [16 KC][12 nf][64 lane][8] bf16 @ 0        (196,608)
//   Qw  [B*T][64] bf16  @ 196608
//   Kw  [B*T][64] bf16  @ 16973824
//   VTw [B][64][256] bf16 @ 33751040

// ---- kernel 0: build pre-fragmented WT --------------------------------------
// WTfrag byte addr (KC*12+nf)*1024 + l*16 holds B-frag: 8 bf16 =
//   W_mat[k = KC*32 + (l>>4)*8 + j][col = (nf&3)*16 + (l&15)],  mat = nf>>2.
__global__ void __launch_bounds__(256) wt_frag_kernel(
        const float* __restrict__ Wq, const float* __restrict__ Wk,
        const float* __restrict__ Wv, bf16* __restrict__ WTfrag) {
    int tid = blockIdx.x * 256 + threadIdx.x;     // 98304 total
    int j  = tid & 7;
    int l  = (tid >> 3) & 63;
    int f  = tid >> 9;            // 0..767 = KC*12 + nf
    int nf = f % 12;
    int KC = f / 12;
    int k   = KC * 32 + (l >> 4) * 8 + j;
    int col = (nf & 3) * 16 + (l & 15);
    const float* W = (nf < 4) ? Wq : ((nf < 8) ? Wk : Wv);
    WTfrag[tid] = (bf16)W[k * 64 + col];
}

// ---- kernel 1: projections (contiguous-staged 2-phase pipeline) -------------
// grid 2048, block 256 (4 waves). Block: 64 rows x 192 cols; K-chunks of 128.
// LDS: x[2][64][128] f32 (2x32KB, verbatim rows, source-XOR-swizzled 16B units)
//      + WT[2][48KB] (verbatim contiguous copy of WTfrag chunk). Total 160 KB.
// Every global load instruction is lane-contiguous (512B+ runs) -> no
// power-of-2-stride channel aliasing.
__global__ void __launch_bounds__(256) proj_kernel(
        const float* __restrict__ x, const bf16* __restrict__ WTfrag,
        bf16* __restrict__ Qw, bf16* __restrict__ Kw, bf16* __restrict__ VTw) {
    __shared__ char smem[163840];

    const int tid = threadIdx.x;
    const int l   = tid & 63;
    const int w   = tid >> 6;
    const int lo  = l & 15;
    const int hi  = l >> 4;
    const int row0 = blockIdx.x * 64;

    // stage x chunk kc -> buffer bx (2048 x 16B units; 8 insts/thread).
    // unit s: row = s>>5, physical 16B-unit uP = s&31.
    // source logical unit uL = (uP&~7) | ((uP&7) ^ (row&7))  [within 128B group]
    auto stage_x = [&](int bx, int kc) {
        #pragma unroll
        for (int j = 0; j < 8; ++j) {
            const int s   = j * 256 + tid;
            const int row = s >> 5;
            const int uP  = s & 31;
            const int uL  = (uP & ~7) | ((uP & 7) ^ (row & 7));
            const char* src = (const char*)(x + (size_t)(row0 + row) * 512 + kc * 128) + uL * 16;
            gload_lds16(src, smem + bx * 32768 + s * 16);
        }
    };
    // stage WT chunk kc -> buffer bw (verbatim 48 KB copy; 12 insts/thread)
    auto stage_w = [&](int bw, int kc) {
        const char* base = (const char*)WTfrag + kc * 49152;
        #pragma unroll
        for (int j = 0; j < 12; ++j) {
            const int s = j * 256 + tid;
            gload_lds16(base + s * 16, smem + 65536 + bw * 49152 + s * 16);
        }
    };

    f32x4 acc[12];
    #pragma unroll
    for (int nf = 0; nf < 12; ++nf) acc[nf] = (f32x4){0.f, 0.f, 0.f, 0.f};

    stage_x(0, 0);
    stage_w(0, 0);

    #pragma unroll 1
    for (int kc = 0; kc < 4; ++kc) {
        const int cur = kc & 1;
        __syncthreads();                         // drain: buffers[cur] ready
        if (kc < 3) { stage_x(cur ^ 1, kc + 1); stage_w(cur ^ 1, kc + 1); }

        #pragma unroll
        for (int KCl = 0; KCl < 4; ++KCl) {
            // A-frag: row w*16+lo, k = KCl*32 + hi*8 .. +8 (two swizzled b128)
            const int rb = ((w * 16 + lo) * 32) << 4;
            const int p1 = (KCl * 8 + ((hi << 1) ^ (lo & 7))) << 4;
            const int p2 = (KCl * 8 + (((hi << 1) | 1) ^ (lo & 7))) << 4;
            f32x4 u0 = *(const f32x4*)(smem + cur * 32768 + rb + p1);
            f32x4 u1 = *(const f32x4*)(smem + cur * 32768 + rb + p2);
            bf16x8 a;
            a[0] = (bf16)u0[0]; a[1] = (bf16)u0[1]; a[2] = (bf16)u0[2]; a[3] = (bf16)u0[3];
            a[4] = (bf16)u1[0]; a[5] = (bf16)u1[1]; a[6] = (bf16)u1[2]; a[7] = (bf16)u1[3];
            // B-frags: 12 lane-contiguous ds_read_b128 (batched)
            bf16x8 bfr[12];
            #pragma unroll
            for (int nf = 0; nf < 12; ++nf)
                bfr[nf] = *(const bf16x8*)(smem + 65536 + cur * 49152 +
                                           ((KCl * 12 + nf) << 10) + (l << 4));
            #pragma unroll
            for (int nf = 0; nf < 12; ++nf)
                acc[nf] = MFMA16(a, bfr[nf], acc[nf]);
        }
    }

    // Epilogue. D-frag: n = lo (+nf*16), m = hi*4 + i. Wave owns rows m0..+16.
    const int m0   = row0 + w * 16;
    const int bidx = m0 >> 8;
    const int t0b  = m0 & 255;
    #pragma unroll
    for (int nf = 0; nf < 12; ++nf) {
        const int nn   = nf * 16 + lo;
        const int mrow = m0 + hi * 4;
        if (nf < 4) {
            #pragma unroll
            for (int i = 0; i < 4; ++i)
                Qw[(mrow + i) * 64 + nn] = (bf16)acc[nf][i];
        } else if (nf < 8) {
            #pragma unroll
            for (int i = 0; i < 4; ++i)
                Kw[(mrow + i) * 64 + (nn - 64)] = (bf16)acc[nf][i];
        } else {
            bf16x4 pk;
            pk[0] = (bf16)acc[nf][0]; pk[1] = (bf16)acc[nf][1];
            pk[2] = (bf16)acc[nf][2]; pk[3] = (bf16)acc[nf][3];
            *(bf16x4*)(VTw + ((bidx * 64 + (nn - 128)) * 256 + t0b + hi * 4)) = pk;
        }
    }
}

// ---- kernel 2: causal flash attention (unchanged, passing) ------------------
__global__ void __launch_bounds__(256, 2) attn_kernel(
        const bf16* __restrict__ Qw, const bf16* __restrict__ Kw,
        const bf16* __restrict__ VTw, float* __restrict__ out) {
    __shared__ bf16 Klds[256][72];
    __shared__ bf16 Plds[4][16][72];

    const int tid = threadIdx.x;
    const int l   = tid & 63;
    const int w   = tid >> 6;
    const int lo  = l & 15;
    const int hi  = l >> 4;
    const int b   = blockIdx.x;

    {
        const bf16* src = Kw + b * (256 * 64);
        const int r0 = tid >> 3;
        const int cc = (tid & 7) * 8;
        #pragma unroll
        for (int p = 0; p < 8; ++p) {
            const int row = p * 32 + r0;
            *(bf16x8*)&Klds[row][cc] = *(const bf16x8*)(src + row * 64 + cc);
        }
    }
    __syncthreads();

    bf16x8 qfr[4][2];
    #pragma unroll
    for (int qf = 0; qf < 4; ++qf)
        #pragma unroll
        for (int ks = 0; ks < 2; ++ks)
            qfr[qf][ks] = *(const bf16x8*)(Qw + b * 16384 +
                              (qf * 64 + w * 16 + lo) * 64 + ks * 32 + hi * 8);

    f32x4 o[4][4];
    #pragma unroll
    for (int qf = 0; qf < 4; ++qf)
        #pragma unroll
        for (int mf = 0; mf < 4; ++mf)
            o[qf][mf] = (f32x4){0.f, 0.f, 0.f, 0.f};
    float m2[4]   = {-INFINITY, -INFINITY, -INFINITY, -INFINITY};
    float lsum[4] = {0.f, 0.f, 0.f, 0.f};

    const float SC = 0.125f * 1.44269504088896340736f;

    #pragma unroll
    for (int kc = 0; kc < 4; ++kc) {
        bf16x8 vf[4][2];
        #pragma unroll
        for (int mf = 0; mf < 4; ++mf)
            #pragma unroll
            for (int ks = 0; ks < 2; ++ks)
                vf[mf][ks] = *(const bf16x8*)(VTw + (b * 64 + mf * 16 + lo) * 256 +
                                              kc * 64 + ks * 32 + hi * 8);

        #pragma unroll
        for (int qf = kc; qf < 4; ++qf) {
            f32x4 s[4];
            #pragma unroll
            for (int kf = 0; kf < 4; ++kf) {
                bf16x8 k0 = *(const bf16x8*)&Klds[kc * 64 + kf * 16 + lo][hi * 8];
                bf16x8 k1 = *(const bf16x8*)&Klds[kc * 64 + kf * 16 + lo][32 + hi * 8];
                f32x4 t = (f32x4){0.f, 0.f, 0.f, 0.f};
                t = MFMA16(k0, qfr[qf][0], t);
                t = MFMA16(k1, qfr[qf][1], t);
                s[kf] = t;
            }
            float mx = -INFINITY;
            #pragma unroll
            for (int kf = 0; kf < 4; ++kf)
                #pragma unroll
                for (int i = 0; i < 4; ++i) {
                    float v = s[kf][i] * SC;
                    if (kc == qf && (kf * 16 + hi * 4 + i) > (w * 16 + lo)) v = -INFINITY;
                    s[kf][i] = v;
                    mx = fmaxf(mx, v);
                }
            mx = fmaxf(mx, __shfl_xor(mx, 16));
            mx = fmaxf(mx, __shfl_xor(mx, 32));
            const float mnew = fmaxf(m2[qf], mx);
            const float rsc  = exp2f(m2[qf] - mnew);
            m2[qf] = mnew;

            float cs = 0.f;
            bf16x4 pk[4];
            #pragma unroll
            for (int kf = 0; kf < 4; ++kf)
                #pragma unroll
                for (int i = 0; i < 4; ++i) {
                    float p = exp2f(s[kf][i] - mnew);
                    cs += p;
                    pk[kf][i] = (bf16)p;
                }
            cs += __shfl_xor(cs, 16);
            cs += __shfl_xor(cs, 32);
            lsum[qf] = lsum[qf] * rsc + cs;

            #pragma unroll
            for (int kf = 0; kf < 4; ++kf)
                *(bf16x4*)&Plds[w][lo][kf * 16 + hi * 4] = pk[kf];

            #pragma unroll
            for (int mf = 0; mf < 4; ++mf) {
                o[qf][mf][0] *= rsc; o[qf][mf][1] *= rsc;
                o[qf][mf][2] *= rsc; o[qf][mf][3] *= rsc;
            }
            #pragma unroll
            for (int ks = 0; ks < 2; ++ks) {
                bf16x8 pf = *(const bf16x8*)&Plds[w][lo][ks * 32 + hi * 8];
                #pragma unroll
                for (int mf = 0; mf < 4; ++mf)
                    o[qf][mf] = MFMA16(vf[mf][ks], pf, o[qf][mf]);
            }
        }
    }

    #pragma unroll
    for (int qf = 0; qf < 4; ++qf) {
        const float inv = 1.0f / lsum[qf];
        const int q = qf * 64 + w * 16 + lo;
        #pragma unroll
        for (int mf = 0; mf < 4; ++mf) {
            f32x4 r4;
            r4[0] = o[qf][mf][0] * inv; r4[1] = o[qf][mf][1] * inv;
            r4[2] = o[qf][mf][2] * inv; r4[3] = o[qf][mf][3] * inv;
            *(f32x4*)(out + (b * 256 + q) * 64 + mf * 16 + hi * 4) = r4;
        }
    }
}

// ---- launcher ---------------------------------------------------------------
extern "C" void kernel_launch(void* const* d_in, const int* in_sizes, int n_in,
                              void* d_out, int out_size, void* d_ws, size_t ws_size,
                              hipStream_t stream) {
    const float* x  = (const float*)d_in[0];
    const float* Wq = (const float*)d_in[1];
    const float* Wk = (const float*)d_in[2];
    const float* Wv = (const float*)d_in[3];
    float* out = (float*)d_out;

    char* ws = (char*)d_ws;
    bf16* WTfrag = (bf16*)(ws);
    bf16* Qw  = (bf16*)(ws + 196608);
    bf16* Kw  = (bf16*)(ws + 16973824);
    bf16* VTw = (bf16*)(ws + 33751040);

    wt_frag_kernel<<<dim3(384), dim3(256), 0, stream>>>(Wq, Wk, Wv, WTfrag);
    proj_kernel<<<dim3(2048), dim3(256), 0, stream>>>(x, WTfrag, Qw, Kw, VTw);
    attn_kernel<<<dim3(512), dim3(256), 0, stream>>>(Qw, Kw, VTw, out);
}